// Round 8
// baseline (223.954 us; speedup 1.0000x reference)
//
#include <hip/hip_runtime.h>
#include <hip/hip_bf16.h>
#include <stdint.h>

typedef __bf16 bf;
typedef __bf16 v8bf __attribute__((ext_vector_type(8)));
typedef float v4f __attribute__((ext_vector_type(4)));

#define SEQ   197
#define HEADS 12
#define HID   768
#define NQKV  2304
#define MTOT  12608   // 64*197

__device__ __forceinline__ void gload_lds16(const void* g, void* l) {
    __builtin_amdgcn_global_load_lds(
        (const __attribute__((address_space(1))) void*)g,
        (__attribute__((address_space(3))) void*)l, 16, 0, 0);
}

// ---------------- kernel 0: fused prep (kx + kwt + kbias in one launch) -----
__global__ void kprep(const float* __restrict__ x, bf* __restrict__ xb,
                      const float* __restrict__ wq, const float* __restrict__ wk,
                      const float* __restrict__ wv, bf* __restrict__ wt,
                      const float* __restrict__ table, float* __restrict__ bias) {
    __shared__ float t[64][65];
    const int bid = blockIdx.x;

    if (bid < 9456) {
        int idx = bid * 256 + threadIdx.x;
        float4 v = ((const float4*)x)[idx];
        bf o[4] = {(bf)v.x, (bf)v.y, (bf)v.z, (bf)v.w};
        ((uint2*)xb)[idx] = *(uint2*)o;
        return;
    }

    if (bid < 9456 + 432) {
        int bz = bid - 9456;
        int z  = bz / 144;
        int rr = bz % 144;
        int bx = rr % 12;
        int by = rr / 12;
        const float* W = (z == 0) ? wq : (z == 1 ? wk : wv);
        int kt = bx * 64, nt = by * 64;
        int r  = threadIdx.x >> 4;
        int c4 = (threadIdx.x & 15) * 4;
#pragma unroll
        for (int p = 0; p < 64; p += 16) {
            float4 v = *(const float4*)(W + (size_t)(kt + p + r) * 768 + nt + c4);
            t[p + r][c4 + 0] = v.x; t[p + r][c4 + 1] = v.y;
            t[p + r][c4 + 2] = v.z; t[p + r][c4 + 3] = v.w;
        }
        __syncthreads();
#pragma unroll
        for (int p = 0; p < 64; p += 16) {
            int i = p + r;
            bf o[4];
#pragma unroll
            for (int j = 0; j < 4; j++) o[j] = (bf)t[c4 + j][i];
            *(uint2*)(wt + (size_t)(z * 768 + nt + i) * 768 + kt + c4) = *(uint2*)o;
        }
        return;
    }

    int idx = (bid - 9888) * 256 + threadIdx.x;
    int h = idx / (208 * 208);
    int r = idx % (208 * 208);
    int i = r / 208, j = r % 208;
    float v = 0.f;
    if (i < SEQ && j < SEQ) {
        int rpi;
        if (i == 0 && j == 0)      rpi = 731;
        else if (i == 0)           rpi = 729;
        else if (j == 0)           rpi = 730;
        else {
            int hp = (i - 1) / 14, wp = (i - 1) % 14;
            int hq = (j - 1) / 14, wq = (j - 1) % 14;
            rpi = (hp - hq + 13) * 27 + (wp - wq + 13);
        }
        v = table[rpi * 12 + h];
    }
    bias[idx] = v;
}

// ---------------- kernel 3: fused QKV GEMM — 256x256, BK=64, 8 waves, -------
// m201-style 4-phase/tile schedule with COUNTED vmcnt (T3+T4), proven XOR
// swizzle (T2), setprio (T5). 2 LDS slots (128 KiB), 1 block/CU.
//
// Key enabler for counted waits with only 2 slots: staging order per tile is
// B-full (rounds 0-3), A-half0 (4-5), A-half1 (6-7), and A's LDS row mapping
// swaps bits 6<->7 of the source row so that phase-g0's A rows {0-63,128-191}
// are the CONTIGUOUS LDS half [0,128). Phases: (g0,ks0),(g0,ks1),(g1,ks0),
// (g1,ks1). Mid-boundary (after ph1) needs A-h1 (4 newer loads -> vmcnt(4));
// end-boundary needs next tile's B+A-h0 (2 newer -> vmcnt(2)). Never 0 until
// the last tile. No __syncthreads in the loop (that was round-1's drain bug).
// Swizzle: byte-identical to the verified-0-conflict round-3 pattern.
__launch_bounds__(512, 1)
__global__ void kgemm(const bf* __restrict__ X, const bf* __restrict__ Wt,
                      const float* __restrict__ bq, const float* __restrict__ bv,
                      bf* __restrict__ C) {
    __shared__ __align__(16) bf sA[2][256 * 64];   // 2 x 32 KiB
    __shared__ __align__(16) bf sB[2][256 * 64];   // 2 x 32 KiB  (128 KiB total)
    const int tid  = threadIdx.x;
    const int wave = tid >> 6, lane = tid & 63;
    const int quad = lane >> 4, l16 = lane & 15;
    const int m0 = blockIdx.x * 256;               // gridDim.x = 50 (last partial)
    const int n0 = blockIdx.y * 256;               // gridDim.y = 9 (exact)
    const int wmb = wave >> 2;                     // 0/1: M group (rows wmb*128..)
    const int wn  = (wave & 3) * 64;               // 4 N groups
    const int swz = l16 & 7;

    // stage round r (0..7) of K-tile kt into slot.
    // r 0-3: B rows [0,256) linear. r 4-7: A lds rows [0,256); src row =
    // bitswap6/7(lds row) so lds half0 = src rows {0-63,128-191} (g0's rows).
    auto stage = [&](int slot, int kt, int r) {
        int cb = (r & 3) * 512 + wave * 64;        // wave-uniform chunk base
        int ch = cb + lane;
        int rl = ch >> 3;                          // lds row 0..255
        int cc = (ch & 7) ^ (rl & 7);              // inverse-swizzled source col
        if (r < 4) {
            gload_lds16(Wt + (size_t)(n0 + rl) * HID + kt * 64 + cc * 8, sB[slot] + cb * 8);
        } else {
            int src  = (rl & 63) | ((rl & 64) << 1) | ((rl & 128) >> 1);
            int arow = m0 + src; if (arow > MTOT - 1) arow = MTOT - 1;
            gload_lds16(X + (size_t)arow * HID + kt * 64 + cc * 8, sA[slot] + cb * 8);
        }
    };

    v4f acc[8][4];
#pragma unroll
    for (int i = 0; i < 8; ++i)
#pragma unroll
        for (int j = 0; j < 4; ++j) acc[i][j] = (v4f){0.f, 0.f, 0.f, 0.f};

    // prologue: tile 0 -> slot 0; need B+A-h0 (rounds 0-5) => 2 newer in flight
#pragma unroll
    for (int r = 0; r < 8; ++r) stage(0, 0, r);
    asm volatile("s_waitcnt vmcnt(2)" ::: "memory");
    __builtin_amdgcn_s_barrier();

#define PH_READ_B(ks)                                                          \
    _Pragma("unroll")                                                          \
    for (int j = 0; j < 4; ++j)                                                \
        bfr[ks][j] = *(const v8bf*)(B + (wn + j * 16 + l16) * 64 +             \
                                    (((ks) * 4 + quad) ^ swz) * 8);
#define PH_READ_A(g, ks)                                                       \
    _Pragma("unroll")                                                          \
    for (int i = 0; i < 4; ++i)                                                \
        afr[i] = *(const v8bf*)(A + ((g) * 128 + wmb * 64 + i * 16 + l16) * 64 + \
                                (((ks) * 4 + quad) ^ swz) * 8);
#define PH_MFMA(g, ks)                                                         \
    __builtin_amdgcn_s_barrier();                                              \
    asm volatile("s_waitcnt lgkmcnt(0)" ::: "memory");                         \
    __builtin_amdgcn_sched_barrier(0);                                         \
    __builtin_amdgcn_s_setprio(1);                                             \
    _Pragma("unroll")                                                          \
    for (int i = 0; i < 4; ++i)                                                \
        _Pragma("unroll")                                                      \
        for (int j = 0; j < 4; ++j)                                            \
            acc[(g) * 4 + i][j] = __builtin_amdgcn_mfma_f32_16x16x32_bf16(     \
                afr[i], bfr[ks][j], acc[(g) * 4 + i][j], 0, 0, 0);             \
    __builtin_amdgcn_s_setprio(0);

#pragma unroll 1
    for (int k = 0; k < 12; ++k) {                 // K = 768 = 12 x 64
        const int slot = k & 1, nslot = slot ^ 1;
        const bf* A = sA[slot];
        const bf* B = sB[slot];
        const bool pf = (k < 11);
        v8bf bfr[2][4];
        v8bf afr[4];

        // ---- phase 0: (g0, ks0) ---- stage next-tile B rows [0,128)
        PH_READ_B(0); PH_READ_A(0, 0);
        if (pf) { stage(nslot, k + 1, 0); stage(nslot, k + 1, 1); }
        PH_MFMA(0, 0);
        __builtin_amdgcn_s_barrier();

        // ---- phase 1: (g0, ks1) ---- stage next-tile B rows [128,256)
        PH_READ_B(1); PH_READ_A(0, 1);
        if (pf) { stage(nslot, k + 1, 2); stage(nslot, k + 1, 3); }
        PH_MFMA(0, 1);
        // mid boundary: need A-h1 of CURRENT tile (staged 3 phases ago)
        if (pf) asm volatile("s_waitcnt vmcnt(4)" ::: "memory");
        else    asm volatile("s_waitcnt vmcnt(0)" ::: "memory");
        __builtin_amdgcn_s_barrier();

        // ---- phase 2: (g1, ks0) ---- stage next-tile A-h0 (B regs reused)
        PH_READ_A(1, 0);
        if (pf) { stage(nslot, k + 1, 4); stage(nslot, k + 1, 5); }
        PH_MFMA(1, 0);
        __builtin_amdgcn_s_barrier();

        // ---- phase 3: (g1, ks1) ---- stage next-tile A-h1
        PH_READ_A(1, 1);
        if (pf) { stage(nslot, k + 1, 6); stage(nslot, k + 1, 7); }
        PH_MFMA(1, 1);
        // end boundary: need next tile's B + A-h0 (2 newer loads in flight)
        if (pf) {
            asm volatile("s_waitcnt vmcnt(2)" ::: "memory");
            __builtin_amdgcn_s_barrier();
        }
    }
#undef PH_READ_B
#undef PH_READ_A
#undef PH_MFMA

    // epilogue
#pragma unroll
    for (int mi = 0; mi < 8; ++mi) {
        int mbase = m0 + wmb * 128 + mi * 16 + quad * 4;
#pragma unroll
        for (int j = 0; j < 4; ++j) {
            int n = n0 + wn + j * 16 + l16;
#pragma unroll
            for (int r = 0; r < 4; ++r) {
                int m = mbase + r;
                if (m < MTOT) {
                    float v = acc[mi][j][r];
                    if (n < 768)        v = (v + bq[n]) * 0.125f;   // Q: +bq, *1/sqrt(64)
                    else if (n >= 1536) v = v + bv[n - 1536];       // V: +bv
                    C[(size_t)m * NQKV + n] = (bf)v;
                }
            }
        }
    }
}

// ---------------- kernel 4: attention — round-6 form (unchanged) ------------
__launch_bounds__(512, 1)
__global__ void kattn(const bf* __restrict__ C, const float* __restrict__ bias,
                      float* __restrict__ out) {
    __shared__ __align__(16) bf sK[208 * 64];      // [kpos][d], XOR-swizzled cols
    __shared__ __align__(16) bf sV[64 * 224];      // transposed [d][kpos]
    __shared__ __align__(16) bf sP[8][16 * 224];   // per-wave P; first 28.7KB = V scratch
    bf* scratch = &sP[0][0];                       // [224][64] linear V staging
    const int tid  = threadIdx.x;
    const int wave = tid >> 6, lane = tid & 63;
    const int quad = lane >> 4, l16 = lane & 15;
    const int b = blockIdx.x / HEADS, h = blockIdx.x % HEADS;
    const bf* Cb = C + (size_t)b * SEQ * NQKV;
    const int swz = l16 & 7;

    // ---- stage K [208][64] swizzled: 1664 chunks of 16B ----
    for (int cb = wave * 64; cb < 1664; cb += 512) {
        int ch  = cb + lane;
        int row = ch >> 3, c = ch & 7;
        int cc  = c ^ (row & 7);
        int s   = row > 196 ? 196 : row;
        gload_lds16(Cb + (size_t)s * NQKV + 768 + h * 64 + cc * 8, sK + cb * 8);
    }
    // ---- stage V [224][64] linear into scratch: 1792 chunks ----
    for (int cb = wave * 64; cb < 1792; cb += 512) {
        int ch  = cb + lane;
        int row = ch >> 3, c = ch & 7;
        int s   = row > 196 ? 196 : row;
        gload_lds16(Cb + (size_t)s * NQKV + 1536 + h * 64 + c * 8, scratch + cb * 8);
    }
    __syncthreads();

    // ---- transpose scratch[224][64] -> sV[64][224] ----
    {
        bf tv[8];
        int chunk = tid;
        for (; chunk < 1792; chunk += 512) {
            int d = chunk & 63, sc = chunk >> 6;
#pragma unroll
            for (int t = 0; t < 8; t++) tv[t] = scratch[(sc * 8 + t) * 64 + d];
            *(uint4*)(sV + d * 224 + sc * 8) = *(uint4*)tv;
        }
    }
    __syncthreads();

    const float* biash = bias + (size_t)h * 208 * 208;

    for (int st = wave; st < 13; st += 8) {
        int s0 = st * 16;
        int qrow = s0 + l16; if (qrow > SEQ - 1) qrow = SEQ - 1;
        v8bf aQ[2];
#pragma unroll
        for (int ks = 0; ks < 2; ks++)
            aQ[ks] = *(const v8bf*)(Cb + (size_t)qrow * NQKV + h * 64 + ks * 32 + quad * 8);

        v4f sc[13];
#pragma unroll
        for (int nt = 0; nt < 13; nt++) {
            v4f a = (v4f){0.f, 0.f, 0.f, 0.f};
#pragma unroll
            for (int ks = 0; ks < 2; ks++) {
                v8bf bK = *(const v8bf*)(sK + (nt * 16 + l16) * 64 + ((ks * 4 + quad) ^ swz) * 8);
                a = __builtin_amdgcn_mfma_f32_16x16x32_bf16(aQ[ks], bK, a, 0, 0, 0);
            }
            sc[nt] = a;
        }
#pragma unroll
        for (int nt = 0; nt < 13; nt++) {
            int j = nt * 16 + l16;
#pragma unroll
            for (int r = 0; r < 4; r++) {
                int i = s0 + quad * 4 + r;
                float v = sc[nt][r] + biash[i * 208 + j];
                if (j >= SEQ) v = -1e30f;
                sc[nt][r] = v;
            }
        }
        float inv[4];
#pragma unroll
        for (int r = 0; r < 4; r++) {
            float m = sc[0][r];
#pragma unroll
            for (int nt = 1; nt < 13; nt++) m = fmaxf(m, sc[nt][r]);
#pragma unroll
            for (int off = 1; off < 16; off <<= 1) m = fmaxf(m, __shfl_xor(m, off, 16));
            float sum = 0.f;
#pragma unroll
            for (int nt = 0; nt < 13; nt++) {
                float e = __expf(sc[nt][r] - m);
                sc[nt][r] = e; sum += e;
            }
#pragma unroll
            for (int off = 1; off < 16; off <<= 1) sum += __shfl_xor(sum, off, 16);
            inv[r] = 1.f / sum;
        }
        bf* P = sP[wave];
#pragma unroll
        for (int nt = 0; nt < 13; nt++) {
            int j = nt * 16 + l16;
#pragma unroll
            for (int r = 0; r < 4; r++)
                P[(quad * 4 + r) * 224 + j] = (bf)sc[nt][r];
        }
        *(uint2*)(P + l16 * 224 + 208 + quad * 4) = make_uint2(0, 0);

        v4f o[4];
#pragma unroll
        for (int n2 = 0; n2 < 4; n2++) o[n2] = (v4f){0.f, 0.f, 0.f, 0.f};
#pragma unroll
        for (int ks = 0; ks < 7; ks++) {
            v8bf aP = *(const v8bf*)(P + l16 * 224 + ks * 32 + quad * 8);
#pragma unroll
            for (int n2 = 0; n2 < 4; n2++) {
                v8bf bV = *(const v8bf*)(sV + (n2 * 16 + l16) * 224 + ks * 32 + quad * 8);
                o[n2] = __builtin_amdgcn_mfma_f32_16x16x32_bf16(aP, bV, o[n2], 0, 0, 0);
            }
        }
#pragma unroll
        for (int r = 0; r < 4; r++) {
            int s = s0 + quad * 4 + r;
            if (s < SEQ) {
#pragma unroll
                for (int n2 = 0; n2 < 4; n2++) {
                    int d = n2 * 16 + l16;
                    out[((size_t)b * SEQ + s) * HID + h * 64 + d] = o[n2][r] * inv[r];
                }
            }
        }
    }
}

// ---------------- launcher (3 launches) -------------------------------------
extern "C" void kernel_launch(void* const* d_in, const int* in_sizes, int n_in,
                              void* d_out, int out_size, void* d_ws, size_t ws_size,
                              hipStream_t stream) {
    const float* X   = (const float*)d_in[0];
    const float* wq  = (const float*)d_in[1];
    const float* bq  = (const float*)d_in[2];
    const float* wk  = (const float*)d_in[3];
    const float* wv  = (const float*)d_in[4];
    const float* bv  = (const float*)d_in[5];
    const float* tbl = (const float*)d_in[6];
    float* out = (float*)d_out;

    char* ws = (char*)d_ws;
    bf*    Xb   = (bf*)ws;                          // 12608*768*2  = 19,365,888 B
    bf*    Wt   = (bf*)(ws + 19365888);             // 2304*768*2   =  3,538,944 B
    bf*    C    = (bf*)(ws + 22904832);             // 12608*2304*2 = 58,097,664 B
    float* bias = (float*)(ws + 81002496);          // 12*208*208*4 =  2,076,672 B

    kprep<<<11916, 256, 0, stream>>>(X, Xb, wq, wk, wv, Wt, tbl, bias);
    dim3 g(50, 9);
    kgemm<<<g, 512, 0, stream>>>(Xb, Wt, bq, bv, C);
    kattn<<<768, 512, 0, stream>>>(C, bias, out);
}